// Round 5
// baseline (1867.478 us; speedup 1.0000x reference)
//
#include <hip/hip_runtime.h>
#include <cstdint>
#include <cstddef>

#define BB 4
#define NN 8192
#define NPP 2048
#define NSS 32
#define CINN 128
#define COUTT 256

typedef float f32x2 __attribute__((ext_vector_type(2)));

// ---------------- DPP reduce helpers (VALU-only cross-lane) ----------------
template<int CTRL>
static __device__ __forceinline__ float dppf(float v){
  return __int_as_float(__builtin_amdgcn_update_dpp(0, __float_as_int(v), CTRL, 0xF, 0xF, true));
}
// full-wave (64) max; valid result in lane 63 (values >= 0; zero-fill benign).
static __device__ __forceinline__ float wave_max63(float v){
  v = fmaxf(v, dppf<0xB1>(v));   // quad_perm xor1
  v = fmaxf(v, dppf<0x4E>(v));   // quad_perm xor2
  v = fmaxf(v, dppf<0x141>(v));  // row_half_mirror (xor7)
  v = fmaxf(v, dppf<0x140>(v));  // row_mirror (xor15)
  v = fmaxf(v, dppf<0x142>(v));  // row_bcast15
  v = fmaxf(v, dppf<0x143>(v));  // row_bcast31
  return v;
}
// reduce within each 8-lane group; all lanes of the group get the result
static __device__ __forceinline__ float red8_maxf(float v){
  v = fmaxf(v, dppf<0xB1>(v));
  v = fmaxf(v, dppf<0x4E>(v));
  v = fmaxf(v, dppf<0x141>(v));
  return v;
}

// ---------- K1: fused FPS (blocks 0..3) + feats transpose + w transpose ----------
__global__ __launch_bounds__(512)
void k_pre(const float* __restrict__ xyz, const float* __restrict__ feats,
           const float* __restrict__ convw,
           int* __restrict__ fidx, float* __restrict__ featsT, float* __restrict__ wT)
{
  __shared__ union {
    struct {
      float  xs[NN];          // 32768 B
      float  ys[NN];
      float  zs[NN];
      float2 slots[2][8];     // (wm, wi) per wave, parity double-buffer
      int    sfidx[NPP];      // fidx staged in LDS; burst store at end
    } fps;
    float tile[32][65];
  } sm;
  const int tid = threadIdx.x;
  const int blk = blockIdx.x;

  if (blk < BB) {
    // ---------------- furthest point sampling, one block per batch ----------------
    const int b = blk;
    float* xs = sm.fps.xs;
    float* ys = sm.fps.ys;
    float* zs = sm.fps.zs;
    for (int n = tid; n < NN; n += 512){
      const float* p = xyz + ((size_t)b*NN + n)*3;
      xs[n] = p[0]; ys[n] = p[1]; zs[n] = p[2];
    }
    __syncthreads();

    // 16 points per lane as 8 f32x2 pairs (register-resident)
    f32x2 PX[8], PY[8], PZ[8], MD[8];
    const int base = tid*16;
    #pragma unroll
    for (int k=0;k<8;++k){
      PX[k].x = xs[base+2*k]; PX[k].y = xs[base+2*k+1];
      PY[k].x = ys[base+2*k]; PY[k].y = ys[base+2*k+1];
      PZ[k].x = zs[base+2*k]; PZ[k].y = zs[base+2*k+1];
      MD[k].x = 3.0e38f;      MD[k].y = 3.0e38f;
    }
    if (tid == 0) sm.fps.sfidx[0] = 0;
    const int lane = tid & 63;
    const int wid  = tid >> 6;

    float cx = xs[0], cy = ys[0], cz = zs[0];

    for (int s = 1; s < NPP; ++s){
      const f32x2 CX = {cx,cx}, CY = {cy,cy}, CZ = {cz,cz};
      float bv = -1.0f; int bi = base;
      #pragma unroll
      for (int k=0;k<8;++k){
        // EXACT reference rounding: d2 = fmaf(dz,dz, fmaf(dy,dy, dx*dx))
        f32x2 dx = PX[k] - CX;
        f32x2 dy = PY[k] - CY;
        f32x2 dz = PZ[k] - CZ;
        f32x2 t  = dx * dx;
        t = __builtin_elementwise_fma(dy, dy, t);
        t = __builtin_elementwise_fma(dz, dz, t);
        const float m0 = fminf(MD[k].x, t.x);
        const float m1 = fminf(MD[k].y, t.y);
        MD[k].x = m0; MD[k].y = m1;
        // pairwise tournament, then combine with running (strict >: first occurrence)
        const bool  h  = m1 > m0;
        const float pm = h ? m1 : m0;
        const int   pi = base + 2*k + (h ? 1 : 0);
        const bool  g  = pm > bv;
        bv = g ? pm : bv;
        bi = g ? pi : bi;
      }

      // wave argmax: DPP value-max, then ballot+ctz for first (lowest-index) match
      float wm = wave_max63(bv);
      wm = __int_as_float(__builtin_amdgcn_readlane(__float_as_int(wm), 63));
      const unsigned long long lm = __ballot(bv == wm);
      const int wl = (int)__builtin_ctzll(lm);            // lane order == index order
      const int wi = __builtin_amdgcn_readlane(bi, wl);

      const int par = s & 1;                 // parity double-buffer -> 1 barrier/step
      if (lane == 0) sm.fps.slots[par][wid] = make_float2(wm, __int_as_float(wi));
      __syncthreads();

      const float2 sv = sm.fps.slots[par][lane & 7];  // one b64 read, replicated per 8-lane group
      const float gm = red8_maxf(sv.x);
      const unsigned long long bm = __ballot(sv.x == gm);
      const int ws = (int)__builtin_ctzll(bm);        // lanes 0..7 hold slots 0..7
      const int cur = __builtin_amdgcn_readlane(__float_as_int(sv.y), ws);
      // winner coords: uniform broadcast reads (conflict-free), r1 pattern
      cx = xs[cur]; cy = ys[cur]; cz = zs[cur];

      if (tid == 0) sm.fps.sfidx[s] = cur;   // LDS only — no VMEM in loop
    }
    __syncthreads();
    for (int i = tid; i < NPP; i += 512) fidx[b*NPP + i] = sm.fps.sfidx[i];
  } else if (blk < BB + 2048) {
    // -------- feats [b][CIN][NN] -> featsT [b][NN][CIN], tile 32x64 --------
    const int tb = blk - BB;
    const int b  = tb >> 9;
    const int t  = tb & 511;
    const int r0 = (t & 3) * 32;     // channel
    const int c0 = (t >> 2) * 64;    // point
    const float* in = feats + (size_t)b*CINN*NN;
    float* outp = featsT + (size_t)b*NN*CINN;
    const int tx = tid & 63, ty = tid >> 6;
    #pragma unroll
    for (int u=0;u<4;++u) sm.tile[ty + 8*u][tx] = in[(size_t)(r0+ty+8*u)*NN + (c0+tx)];
    __syncthreads();
    const int tx2 = tid & 31, ty2 = tid >> 5;
    #pragma unroll
    for (int u=0;u<4;++u) outp[(size_t)(c0+ty2+16*u)*CINN + (r0+tx2)] = sm.tile[tx2][ty2+16*u];
  } else {
    // -------- conv_w [COUT][CIN] -> wT [CIN][COUT], tile 32x64 --------
    const int t  = blk - BB - 2048;
    const int r0 = (t >> 1) * 32;    // o
    const int c0 = (t & 1) * 64;     // c
    const int tx = tid & 63, ty = tid >> 6;
    #pragma unroll
    for (int u=0;u<4;++u) sm.tile[ty+8*u][tx] = convw[(size_t)(r0+ty+8*u)*CINN + (c0+tx)];
    __syncthreads();
    const int tx2 = tid & 31, ty2 = tid >> 5;
    #pragma unroll
    for (int u=0;u<4;++u) wT[(size_t)(c0+ty2+16*u)*COUTT + (r0+tx2)] = sm.tile[tx2][ty2+16*u];
  }
}

// ---------- K2: ball query — one wave per query; 4 chunks (256 pts) per dependent round ----------
__global__ __launch_bounds__(256)
void k_ball(const float* __restrict__ xyz, const int* __restrict__ fidx, int* __restrict__ idxb)
{
  const int lane = threadIdx.x & 63;
  const int gw = blockIdx.x*4 + (threadIdx.x >> 6);   // 0..8191 = b*NP + p
  const int b = gw >> 11;
  const int qi = fidx[gw];
  const float R2F = (float)(0.2 * 0.2);               // exact jax weak-type promotion
  const float* q = xyz + ((size_t)b*NN + qi)*3;
  const float qx = q[0], qy = q[1], qz = q[2];
  const float* Bp = xyz + (size_t)b*NN*3;
  int* outp = idxb + (size_t)gw*NSS;
  int cnt = 0, first = -1;
  for (int base0 = 0; base0 < NN; base0 += 256){
    float d2u[4];
    #pragma unroll
    for (int u=0;u<4;++u){
      const float* P = Bp + (size_t)(base0 + u*64 + lane)*3;
      const float dx = P[0]-qx, dy = P[1]-qy, dz = P[2]-qz;
      d2u[u] = fmaf(dz,dz, fmaf(dy,dy, dx*dx));
    }
    #pragma unroll
    for (int u=0;u<4;++u){
      const bool hit = d2u[u] < R2F;
      const unsigned long long m = __ballot(hit);
      if (first < 0 && m != 0ull) first = base0 + u*64 + (int)__builtin_ctzll(m);
      const int slot = cnt + (int)__popcll(m & ((1ull<<lane)-1ull));
      if (hit && slot < NSS) outp[slot] = base0 + u*64 + lane;
      cnt += (int)__popcll(m);
    }
    if (cnt >= NSS) break;
  }
  if (cnt < NSS){
    const int f = (first >= 0) ? first : 0;           // reference fallback semantics
    if (lane >= cnt && lane < NSS) outp[lane] = f;
  }
}

// ---------- K3: gather + max-pool; half-wave per query; write pooledC[b][c][p] ----------
__global__ __launch_bounds__(256)
void k_pool(const float* __restrict__ featsT, const int* __restrict__ idxb, float* __restrict__ pooledC)
{
  __shared__ int lidx[256];
  const int tid = threadIdx.x;
  const int blk = blockIdx.x;                 // 1024 blocks, 8 queries each
  lidx[tid] = idxb[(size_t)blk*256 + tid];
  __syncthreads();
  const int hw = tid >> 5, l = tid & 31;
  const int q = blk*8 + hw;
  const int b = q >> 11, p = q & (NPP-1);
  const float4* basep = (const float4*)(featsT + (size_t)b*NN*CINN);
  float4 m = make_float4(-3e38f,-3e38f,-3e38f,-3e38f);
  #pragma unroll 8
  for (int s=0;s<NSS;++s){
    const int i = lidx[hw*32 + s];
    const float4 v = basep[(size_t)i*32 + l]; // coalesced 512B row per point
    m.x = fmaxf(m.x, v.x); m.y = fmaxf(m.y, v.y);
    m.z = fmaxf(m.z, v.z); m.w = fmaxf(m.w, v.w);
  }
  float* oc = pooledC + ((size_t)b*CINN + l*4)*NPP + p;
  oc[0] = m.x; oc[NPP] = m.y; oc[2*(size_t)NPP] = m.z; oc[3*(size_t)NPP] = m.w;
}

// ---------- K4: GEMM (wT coalesced, pooledC uniform/scalar) + BN + LeakyReLU ----------
__global__ __launch_bounds__(256)
void k_gemm(const float* __restrict__ pooledC, const float* __restrict__ wT,
            const float* __restrict__ gamma, const float* __restrict__ beta,
            const float* __restrict__ rmean, const float* __restrict__ rvar,
            float* __restrict__ out)
{
  const int o = threadIdx.x;                 // 0..255 = output channel
  const int blk = blockIdx.x;                // 512 blocks
  const int b = blk >> 7;
  const int p0 = (blk & 127) << 4;           // 16 points per block
  const float* pc = pooledC + (size_t)b*CINN*NPP + p0;
  float acc[16];
  #pragma unroll
  for (int i=0;i<16;++i) acc[i]=0.f;
  #pragma unroll 4
  for (int c=0;c<CINN;++c){
    const float wv = wT[c*COUTT + o];                       // coalesced across block
    const float4* pr = (const float4*)(pc + (size_t)c*NPP); // uniform address
    #pragma unroll
    for (int qq=0;qq<4;++qq){
      const float4 pv = pr[qq];
      acc[4*qq+0] = fmaf(wv, pv.x, acc[4*qq+0]);
      acc[4*qq+1] = fmaf(wv, pv.y, acc[4*qq+1]);
      acc[4*qq+2] = fmaf(wv, pv.z, acc[4*qq+2]);
      acc[4*qq+3] = fmaf(wv, pv.w, acc[4*qq+3]);
    }
  }
  const float inv = gamma[o] / sqrtf(rvar[o] + 1e-5f);
  const float sh  = beta[o] - rmean[o]*inv;
  float4* op = (float4*)(out + ((size_t)b*COUTT + o)*NPP + p0);
  #pragma unroll
  for (int qq=0;qq<4;++qq){
    float4 y;
    float t0 = fmaf(acc[4*qq+0], inv, sh);
    float t1 = fmaf(acc[4*qq+1], inv, sh);
    float t2 = fmaf(acc[4*qq+2], inv, sh);
    float t3 = fmaf(acc[4*qq+3], inv, sh);
    y.x = t0 >= 0.f ? t0 : 0.2f*t0;
    y.y = t1 >= 0.f ? t1 : 0.2f*t1;
    y.z = t2 >= 0.f ? t2 : 0.2f*t2;
    y.w = t3 >= 0.f ? t3 : 0.2f*t3;
    op[qq] = y;
  }
}

extern "C" void kernel_launch(void* const* d_in, const int* in_sizes, int n_in,
                              void* d_out, int out_size, void* d_ws, size_t ws_size,
                              hipStream_t stream)
{
  (void)in_sizes; (void)n_in; (void)out_size; (void)ws_size;
  const float* xyz   = (const float*)d_in[0];
  const float* feats = (const float*)d_in[1];
  const float* convw = (const float*)d_in[2];
  const float* gamma = (const float*)d_in[3];
  const float* beta  = (const float*)d_in[4];
  const float* rmean = (const float*)d_in[5];
  const float* rvar  = (const float*)d_in[6];
  float* out = (float*)d_out;

  char* ws = (char*)d_ws;
  float* featsT  = (float*)(ws);                                  // 16,777,216 B
  float* pooledC = (float*)(ws + 16777216);                       //  4,194,304 B
  float* wT      = (float*)(ws + 16777216 + 4194304);             //    131,072 B
  int*   fidx    = (int*)  (ws + 16777216 + 4194304 + 131072);    //     32,768 B
  int*   idxb    = (int*)  (ws + 16777216 + 4194304 + 131072 + 32768); // 1,048,576 B

  k_pre <<<dim3(BB + 2048 + 16), dim3(512), 0, stream>>>(xyz, feats, convw, fidx, featsT, wT);
  k_ball<<<dim3(2048),           dim3(256), 0, stream>>>(xyz, fidx, idxb);
  k_pool<<<dim3(1024),           dim3(256), 0, stream>>>(featsT, idxb, pooledC);
  k_gemm<<<dim3(512),            dim3(256), 0, stream>>>(pooledC, wT, gamma, beta, rmean, rvar, out);
}

// Round 6
// 1600.962 us; speedup vs baseline: 1.1665x; 1.1665x over previous
//
#include <hip/hip_runtime.h>
#include <cstdint>
#include <cstddef>

#define BB 4
#define NN 8192
#define NPP 2048
#define NSS 32
#define CINN 128
#define COUTT 256

// ---------------- DPP reduce helpers (VALU-only cross-lane) ----------------
template<int CTRL>
static __device__ __forceinline__ int dppi(int v){
  return __builtin_amdgcn_update_dpp(0, v, CTRL, 0xF, 0xF, true);
}
template<int CTRL>
static __device__ __forceinline__ float dppf(float v){
  return __int_as_float(__builtin_amdgcn_update_dpp(0, __float_as_int(v), CTRL, 0xF, 0xF, true));
}
// full-wave (64) max; valid result in lane 63. Values must be >= 0 (true here).
static __device__ __forceinline__ float wave_max63(float v){
  v = fmaxf(v, dppf<0xB1>(v));   // quad_perm xor1
  v = fmaxf(v, dppf<0x4E>(v));   // quad_perm xor2
  v = fmaxf(v, dppf<0x141>(v));  // row_half_mirror (xor7)
  v = fmaxf(v, dppf<0x140>(v));  // row_mirror (xor15)
  v = fmaxf(v, dppf<0x142>(v));  // row_bcast15
  v = fmaxf(v, dppf<0x143>(v));  // row_bcast31
  return v;
}
static __device__ __forceinline__ int wave_mini63(int v){
  v = min(v, dppi<0xB1>(v));
  v = min(v, dppi<0x4E>(v));
  v = min(v, dppi<0x141>(v));
  v = min(v, dppi<0x140>(v));
  v = min(v, dppi<0x142>(v));
  v = min(v, dppi<0x143>(v));
  return v;
}
// reduce within each 8-lane group; all lanes of the group get the result
static __device__ __forceinline__ float red8_maxf(float v){
  v = fmaxf(v, dppf<0xB1>(v));
  v = fmaxf(v, dppf<0x4E>(v));
  v = fmaxf(v, dppf<0x141>(v));
  return v;
}
static __device__ __forceinline__ int red8_mini(int v){
  v = min(v, dppi<0xB1>(v));
  v = min(v, dppi<0x4E>(v));
  v = min(v, dppi<0x141>(v));
  return v;
}

// ---------- K1: fused FPS (blocks 0..3) + feats transpose + w transpose ----------
// k_pre is byte-for-byte the round-1 version (measured 1485 us).
__global__ __launch_bounds__(512)
void k_pre(const float* __restrict__ xyz, const float* __restrict__ feats,
           const float* __restrict__ convw,
           int* __restrict__ fidx, float* __restrict__ featsT, float* __restrict__ wT)
{
  __shared__ float smem[3*NN + 64];   // 96KB: xs/ys/zs + reduce slots (FPS) | reused as transpose tile
  const int tid = threadIdx.x;
  const int blk = blockIdx.x;

  if (blk < BB) {
    // ---------------- furthest point sampling, one block per batch ----------------
    const int b = blk;
    float* xs = smem;
    float* ys = smem + NN;
    float* zs = smem + 2*NN;
    float2* slots = (float2*)(smem + 3*NN);   // [2 parity][8 waves]

    for (int n = tid; n < NN; n += 512){
      const float* p = xyz + ((size_t)b*NN + n)*3;
      xs[n] = p[0]; ys[n] = p[1]; zs[n] = p[2];
    }
    __syncthreads();

    float px[16], py[16], pz[16], mind[16];
    const int base = tid*16;
    #pragma unroll
    for (int j=0;j<16;++j){
      px[j]=xs[base+j]; py[j]=ys[base+j]; pz[j]=zs[base+j];
      mind[j]=3.0e38f;
    }
    int cur = 0;
    if (tid == 0) fidx[b*NPP] = 0;
    const int lane = tid & 63;
    const int wid  = tid >> 6;

    for (int s = 1; s < NPP; ++s){
      const float cx = xs[cur], cy = ys[cur], cz = zs[cur];
      float bv = -1.0f; int bj = 0;
      #pragma unroll
      for (int j=0;j<16;++j){
        // EXACT reference formula class: ((dx*dx)+dy*dy)+dz*dz with fma fusion
        const float dx = px[j]-cx, dy = py[j]-cy, dz = pz[j]-cz;
        const float d2 = fmaf(dz,dz, fmaf(dy,dy, dx*dx));
        const float m  = fminf(mind[j], d2);
        mind[j] = m;
        const bool g = m > bv;     // strict >: keeps earliest index on tie
        bv = g ? m : bv;
        bj = g ? j : bj;
      }
      const int bi = base + bj;

      // wave-level argmax: phase 1 max value, phase 2 min index among matches
      float wm = wave_max63(bv);
      wm = __int_as_float(__builtin_amdgcn_readlane(__float_as_int(wm), 63));
      int cand = (bv == wm) ? bi : 0x7FFFFFFF;
      int wi = wave_mini63(cand);
      wi = __builtin_amdgcn_readlane(wi, 63);

      const int par = s & 1;                       // parity double-buffer -> 1 barrier/step
      if (lane == 0) slots[par*8 + wid] = make_float2(wm, __int_as_float(wi));
      __syncthreads();

      const float2 sv = slots[par*8 + (lane & 7)]; // data replicated into every 8-lane group
      const float v8 = sv.x;
      const int   i8 = __float_as_int(sv.y);
      const float gm = red8_maxf(v8);
      const int   c8 = (v8 == gm) ? i8 : 0x7FFFFFFF;
      cur = red8_mini(c8);                          // identical in all lanes/waves

      if (tid == 0) fidx[b*NPP + s] = cur;
    }
  } else if (blk < BB + 2048) {
    // -------- feats [b][CIN][NN] -> featsT [b][NN][CIN], tile 32x64 --------
    const int tb = blk - BB;
    const int b  = tb >> 9;
    const int t  = tb & 511;
    const int r0 = (t & 3) * 32;     // channel
    const int c0 = (t >> 2) * 64;    // point
    const float* in = feats + (size_t)b*CINN*NN;
    float* outp = featsT + (size_t)b*NN*CINN;
    float (*tile)[65] = (float(*)[65])smem;
    const int tx = tid & 63, ty = tid >> 6;
    #pragma unroll
    for (int u=0;u<4;++u) tile[ty + 8*u][tx] = in[(size_t)(r0+ty+8*u)*NN + (c0+tx)];
    __syncthreads();
    const int tx2 = tid & 31, ty2 = tid >> 5;
    #pragma unroll
    for (int u=0;u<4;++u) outp[(size_t)(c0+ty2+16*u)*CINN + (r0+tx2)] = tile[tx2][ty2+16*u];
  } else {
    // -------- conv_w [COUT][CIN] -> wT [CIN][COUT], tile 32x64 --------
    const int t  = blk - BB - 2048;
    const int r0 = (t >> 1) * 32;    // o
    const int c0 = (t & 1) * 64;     // c
    float (*tile)[65] = (float(*)[65])smem;
    const int tx = tid & 63, ty = tid >> 6;
    #pragma unroll
    for (int u=0;u<4;++u) tile[ty+8*u][tx] = convw[(size_t)(r0+ty+8*u)*CINN + (c0+tx)];
    __syncthreads();
    const int tx2 = tid & 31, ty2 = tid >> 5;
    #pragma unroll
    for (int u=0;u<4;++u) wT[(size_t)(c0+ty2+16*u)*COUTT + (r0+tx2)] = tile[tx2][ty2+16*u];
  }
}

// ---------- K2: ball query — one wave per query; 4 chunks (256 pts) per dependent round ----------
__global__ __launch_bounds__(256)
void k_ball(const float* __restrict__ xyz, const int* __restrict__ fidx, int* __restrict__ idxb)
{
  const int lane = threadIdx.x & 63;
  const int gw = blockIdx.x*4 + (threadIdx.x >> 6);   // 0..8191 = b*NP + p
  const int b = gw >> 11;
  const int qi = fidx[gw];
  const float R2F = (float)(0.2 * 0.2);               // exact jax weak-type promotion
  const float* q = xyz + ((size_t)b*NN + qi)*3;
  const float qx = q[0], qy = q[1], qz = q[2];
  const float* Bp = xyz + (size_t)b*NN*3;
  int* outp = idxb + (size_t)gw*NSS;
  int cnt = 0, first = -1;
  for (int base0 = 0; base0 < NN; base0 += 256){
    float d2u[4];
    #pragma unroll
    for (int u=0;u<4;++u){
      const float* P = Bp + (size_t)(base0 + u*64 + lane)*3;
      const float dx = P[0]-qx, dy = P[1]-qy, dz = P[2]-qz;
      d2u[u] = fmaf(dz,dz, fmaf(dy,dy, dx*dx));
    }
    #pragma unroll
    for (int u=0;u<4;++u){
      const bool hit = d2u[u] < R2F;
      const unsigned long long m = __ballot(hit);
      if (first < 0 && m != 0ull) first = base0 + u*64 + (int)__builtin_ctzll(m);
      const int slot = cnt + (int)__popcll(m & ((1ull<<lane)-1ull));
      if (hit && slot < NSS) outp[slot] = base0 + u*64 + lane;
      cnt += (int)__popcll(m);
    }
    if (cnt >= NSS) break;
  }
  if (cnt < NSS){
    const int f = (first >= 0) ? first : 0;           // reference fallback semantics
    if (lane >= cnt && lane < NSS) outp[lane] = f;
  }
}

// ---------- K3: gather + max-pool; half-wave per query; write pooledC[b][c][p] ----------
__global__ __launch_bounds__(256)
void k_pool(const float* __restrict__ featsT, const int* __restrict__ idxb, float* __restrict__ pooledC)
{
  __shared__ int lidx[256];
  const int tid = threadIdx.x;
  const int blk = blockIdx.x;                 // 1024 blocks, 8 queries each
  lidx[tid] = idxb[(size_t)blk*256 + tid];
  __syncthreads();
  const int hw = tid >> 5, l = tid & 31;
  const int q = blk*8 + hw;
  const int b = q >> 11, p = q & (NPP-1);
  const float4* basep = (const float4*)(featsT + (size_t)b*NN*CINN);
  float4 m = make_float4(-3e38f,-3e38f,-3e38f,-3e38f);
  #pragma unroll 8
  for (int s=0;s<NSS;++s){
    const int i = lidx[hw*32 + s];
    const float4 v = basep[(size_t)i*32 + l]; // coalesced 512B row per point
    m.x = fmaxf(m.x, v.x); m.y = fmaxf(m.y, v.y);
    m.z = fmaxf(m.z, v.z); m.w = fmaxf(m.w, v.w);
  }
  float* oc = pooledC + ((size_t)b*CINN + l*4)*NPP + p;
  oc[0] = m.x; oc[NPP] = m.y; oc[2*(size_t)NPP] = m.z; oc[3*(size_t)NPP] = m.w;
}

// ---------- K4: GEMM (wT coalesced, pooledC uniform/scalar) + BN + LeakyReLU ----------
__global__ __launch_bounds__(256)
void k_gemm(const float* __restrict__ pooledC, const float* __restrict__ wT,
            const float* __restrict__ gamma, const float* __restrict__ beta,
            const float* __restrict__ rmean, const float* __restrict__ rvar,
            float* __restrict__ out)
{
  const int o = threadIdx.x;                 // 0..255 = output channel
  const int blk = blockIdx.x;                // 512 blocks
  const int b = blk >> 7;
  const int p0 = (blk & 127) << 4;           // 16 points per block
  const float* pc = pooledC + (size_t)b*CINN*NPP + p0;
  float acc[16];
  #pragma unroll
  for (int i=0;i<16;++i) acc[i]=0.f;
  #pragma unroll 4
  for (int c=0;c<CINN;++c){
    const float wv = wT[c*COUTT + o];                       // coalesced across block
    const float4* pr = (const float4*)(pc + (size_t)c*NPP); // uniform address
    #pragma unroll
    for (int qq=0;qq<4;++qq){
      const float4 pv = pr[qq];
      acc[4*qq+0] = fmaf(wv, pv.x, acc[4*qq+0]);
      acc[4*qq+1] = fmaf(wv, pv.y, acc[4*qq+1]);
      acc[4*qq+2] = fmaf(wv, pv.z, acc[4*qq+2]);
      acc[4*qq+3] = fmaf(wv, pv.w, acc[4*qq+3]);
    }
  }
  const float inv = gamma[o] / sqrtf(rvar[o] + 1e-5f);
  const float sh  = beta[o] - rmean[o]*inv;
  float4* op = (float4*)(out + ((size_t)b*COUTT + o)*NPP + p0);
  #pragma unroll
  for (int qq=0;qq<4;++qq){
    float4 y;
    float t0 = fmaf(acc[4*qq+0], inv, sh);
    float t1 = fmaf(acc[4*qq+1], inv, sh);
    float t2 = fmaf(acc[4*qq+2], inv, sh);
    float t3 = fmaf(acc[4*qq+3], inv, sh);
    y.x = t0 >= 0.f ? t0 : 0.2f*t0;
    y.y = t1 >= 0.f ? t1 : 0.2f*t1;
    y.z = t2 >= 0.f ? t2 : 0.2f*t2;
    y.w = t3 >= 0.f ? t3 : 0.2f*t3;
    op[qq] = y;
  }
}

extern "C" void kernel_launch(void* const* d_in, const int* in_sizes, int n_in,
                              void* d_out, int out_size, void* d_ws, size_t ws_size,
                              hipStream_t stream)
{
  (void)in_sizes; (void)n_in; (void)out_size; (void)ws_size;
  const float* xyz   = (const float*)d_in[0];
  const float* feats = (const float*)d_in[1];
  const float* convw = (const float*)d_in[2];
  const float* gamma = (const float*)d_in[3];
  const float* beta  = (const float*)d_in[4];
  const float* rmean = (const float*)d_in[5];
  const float* rvar  = (const float*)d_in[6];
  float* out = (float*)d_out;

  char* ws = (char*)d_ws;
  float* featsT  = (float*)(ws);                                  // 16,777,216 B
  float* pooledC = (float*)(ws + 16777216);                       //  4,194,304 B
  float* wT      = (float*)(ws + 16777216 + 4194304);             //    131,072 B
  int*   fidx    = (int*)  (ws + 16777216 + 4194304 + 131072);    //     32,768 B
  int*   idxb    = (int*)  (ws + 16777216 + 4194304 + 131072 + 32768); // 1,048,576 B

  k_pre <<<dim3(BB + 2048 + 16), dim3(512), 0, stream>>>(xyz, feats, convw, fidx, featsT, wT);
  k_ball<<<dim3(2048),           dim3(256), 0, stream>>>(xyz, fidx, idxb);
  k_pool<<<dim3(1024),           dim3(256), 0, stream>>>(featsT, idxb, pooledC);
  k_gemm<<<dim3(512),            dim3(256), 0, stream>>>(pooledC, wT, gamma, beta, rmean, rvar, out);
}